// Round 3
// baseline (272.632 us; speedup 1.0000x reference)
//
#include <hip/hip_runtime.h>
#include <hip/hip_cooperative_groups.h>
#include <cstddef>
#include <cstdint>

namespace cg = cooperative_groups;

// EdgeSheafLaplacian: n=1024 nodes, stalk d=8, P=32768 directed edges.
// Output Delta (8192 x 8192) f32: only 1024 diag + P edge blocks nonzero.
//
// R3: single cooperative kernel. The 268MB zero-fill (41us BW floor) runs on
// writer blocks WHILE compute blocks build diag -> Newton-Schulz D^{-1/2}.
// Reverse edge is structural (directed = [lo,hi ; hi,lo] concat): rev = p +- P/2,
// verified in-kernel. After grid.sync, all waves compute + scatter the 8.65MB
// of nonzero normalized blocks over the zeros.

namespace {
constexpr int N = 1024;
constexpr int Dd = 8;
constexpr int ND = N * Dd;        // 8192
constexpr int GRID = 1024;        // blocks (4 waves each) — co-resident
constexpr int CBLK = 256;         // compute blocks (1024 waves = N)
constexpr int TPB = 256;
constexpr int CHUNK_F4 = 4096;    // 64 KiB zero-fill chunk
constexpr int NCHUNKS = (ND * ND / 4) / CHUNK_F4;  // 4096
using f4 = __attribute__((ext_vector_type(4))) float;
}

__device__ __forceinline__ void sub_barrier(int* cnt, int nblk) {
  __syncthreads();
  if (threadIdx.x == 0) {
    __hip_atomic_fetch_add(cnt, 1, __ATOMIC_ACQ_REL, __HIP_MEMORY_SCOPE_AGENT);
    while (__hip_atomic_load(cnt, __ATOMIC_ACQUIRE, __HIP_MEMORY_SCOPE_AGENT) < nblk) {
    }
  }
  __syncthreads();
}

__global__ __launch_bounds__(256, 4) void fused(
    const float* __restrict__ R, const int* __restrict__ eidx,
    const float* __restrict__ L1, int P, int* __restrict__ cnt,
    float* __restrict__ diag, float* __restrict__ Dis, float* __restrict__ out) {
  const int tid = threadIdx.x;
  const int bid = blockIdx.x;
  const int lane = tid & 63;
  const int a = lane >> 3, b = lane & 7;
  __shared__ int sChunk;

  if (bid < CBLK) {
    // ---- build: FtF = R^T R, accumulate diag[i] ----
    int wave = ((bid << 8) + tid) >> 6;  // 0..1023
    for (int u = wave; u < P; u += CBLK * (TPB / 64)) {
      int i = eidx[2 * u];
      float r = R[(size_t)u * 64 + lane];
      float acc = 0.f;
#pragma unroll
      for (int k = 0; k < 8; ++k)
        acc += __shfl(r, k * 8 + a, 64) * __shfl(r, k * 8 + b, 64);
      atomicAdd(&diag[i * 64 + lane], acc);
    }
    sub_barrier(cnt, CBLK);
    // ---- Newton-Schulz D^{-1/2}: one node per wave (exactly N waves) ----
    int v = wave;
    float dv = diag[v * 64 + lane];
    float dvt = __shfl(dv, b * 8 + a, 64);
    float A = 0.5f * (dv + dvt) + (a == b ? 1e-4f : 0.f);
    float sq = A * A;
#pragma unroll
    for (int off = 32; off; off >>= 1) sq += __shfl_xor(sq, off, 64);
    float fro = sqrtf(sq);
    float Y = A * (1.f / fro);
    float Z = (a == b) ? 1.f : 0.f;
    for (int it = 0; it < 18; ++it) {
      float T = 0.f;
#pragma unroll
      for (int k = 0; k < 8; ++k)
        T += __shfl(Z, a * 8 + k, 64) * __shfl(Y, k * 8 + b, 64);
      float G = ((a == b) ? 1.5f : 0.f) - 0.5f * T;
      float Yn = 0.f, Zn = 0.f;
#pragma unroll
      for (int k = 0; k < 8; ++k) {
        Yn += __shfl(Y, a * 8 + k, 64) * __shfl(G, k * 8 + b, 64);
        Zn += __shfl(G, a * 8 + k, 64) * __shfl(Z, k * 8 + b, 64);
      }
      Y = Yn;
      Z = Zn;
    }
    Dis[v * 64 + lane] = Z * (1.f / sqrtf(fro));
  }

  // ---- zero-fill work queue: writers from t=0; compute blocks join late ----
  for (;;) {
    __syncthreads();
    if (tid == 0) sChunk = atomicAdd(&cnt[1], 1);
    __syncthreads();
    int c = sChunk;
    if (c >= NCHUNKS) break;
    f4* base = (f4*)out + (size_t)c * CHUNK_F4;
    f4 z = {0.f, 0.f, 0.f, 0.f};
#pragma unroll
    for (int t = 0; t < CHUNK_F4 / TPB; ++t)
      __builtin_nontemporal_store(z, base + t * TPB + tid);
  }

  cg::this_grid().sync();

  // ---- scatter normalized nonzero blocks over the zeros ----
  int gwave = ((bid << 8) + tid) >> 6;             // 0..4095
  const int nw = GRID * (TPB / 64);                // 4096
  for (int u = gwave; u < P + N; u += nw) {
    int i, j;
    float M;
    if (u < P) {
      int p = u;
      i = eidx[2 * p];
      j = eidx[2 * p + 1];
      int rev = (p < P / 2) ? p + P / 2 : p - P / 2;  // structural reverse edge
      bool ok = (eidx[2 * rev] == j) && (eidx[2 * rev + 1] == i);
      float l1v = L1[i * N + j];
      float sgn = (l1v > 0.f ? 1.f : 0.f) - (l1v < 0.f ? 1.f : 0.f);
      if (!ok || sgn == 0.f) continue;  // block is exactly zero (already filled)
      float rp = R[(size_t)p * 64 + lane];
      float rr = R[(size_t)rev * 64 + lane];
      float m = 0.f;
#pragma unroll
      for (int k = 0; k < 8; ++k)
        m += __shfl(rr, k * 8 + a, 64) * __shfl(rp, k * 8 + b, 64);
      M = -sgn * m;
    } else {
      int v = u - P;
      i = v;
      j = v;
      M = diag[v * 64 + lane];
    }
    float di = Dis[i * 64 + lane];
    float dj = Dis[j * 64 + lane];
    float T = 0.f;
#pragma unroll
    for (int k = 0; k < 8; ++k)
      T += __shfl(M, a * 8 + k, 64) * __shfl(dj, k * 8 + b, 64);
    float o = 0.f;
#pragma unroll
    for (int k = 0; k < 8; ++k)
      o += __shfl(di, a * 8 + k, 64) * __shfl(T, k * 8 + b, 64);
    out[(size_t)(i * Dd + a) * ND + (j * Dd + b)] = o;
  }
}

// ---------------- fallback path (non-cooperative), R1-style ----------------
__global__ void k_build(const float* __restrict__ R, const int* __restrict__ eidx,
                        int P, float* __restrict__ diag) {
  int gid = blockIdx.x * blockDim.x + threadIdx.x;
  int u = gid >> 6;
  if (u >= P) return;
  int lane = gid & 63;
  int a = lane >> 3, b = lane & 7;
  int i = eidx[2 * u];
  float r = R[(size_t)u * 64 + lane];
  float acc = 0.f;
#pragma unroll
  for (int k = 0; k < 8; ++k)
    acc += __shfl(r, k * 8 + a, 64) * __shfl(r, k * 8 + b, 64);
  atomicAdd(&diag[i * 64 + lane], acc);
}

__global__ void k_invsqrt(const float* __restrict__ diag, float* __restrict__ Dis) {
  int gid = blockIdx.x * blockDim.x + threadIdx.x;
  int v = gid >> 6;
  if (v >= N) return;
  int lane = gid & 63;
  int a = lane >> 3, b = lane & 7;
  float dv = diag[v * 64 + lane];
  float dvt = __shfl(dv, b * 8 + a, 64);
  float A = 0.5f * (dv + dvt) + (a == b ? 1e-4f : 0.f);
  float sq = A * A;
#pragma unroll
  for (int off = 32; off; off >>= 1) sq += __shfl_xor(sq, off, 64);
  float fro = sqrtf(sq);
  float Y = A * (1.f / fro);
  float Z = (a == b) ? 1.f : 0.f;
  for (int it = 0; it < 18; ++it) {
    float T = 0.f;
#pragma unroll
    for (int k = 0; k < 8; ++k)
      T += __shfl(Z, a * 8 + k, 64) * __shfl(Y, k * 8 + b, 64);
    float G = ((a == b) ? 1.5f : 0.f) - 0.5f * T;
    float Yn = 0.f, Zn = 0.f;
#pragma unroll
    for (int k = 0; k < 8; ++k) {
      Yn += __shfl(Y, a * 8 + k, 64) * __shfl(G, k * 8 + b, 64);
      Zn += __shfl(G, a * 8 + k, 64) * __shfl(Z, k * 8 + b, 64);
    }
    Y = Yn;
    Z = Zn;
  }
  Dis[v * 64 + lane] = Z * (1.f / sqrtf(fro));
}

__global__ void k_blocks(const float* __restrict__ R, const int* __restrict__ eidx,
                         const float* __restrict__ L1, const float* __restrict__ diag,
                         const float* __restrict__ Dis, int P,
                         float* __restrict__ out) {
  int gid = blockIdx.x * blockDim.x + threadIdx.x;
  int u = gid >> 6;
  if (u >= P + N) return;
  int lane = gid & 63;
  int a = lane >> 3, b = lane & 7;
  int i, j;
  float M;
  if (u < P) {
    int p = u;
    i = eidx[2 * p];
    j = eidx[2 * p + 1];
    int rev = (p < P / 2) ? p + P / 2 : p - P / 2;
    bool ok = (eidx[2 * rev] == j) && (eidx[2 * rev + 1] == i);
    float l1v = L1[i * N + j];
    float sgn = (l1v > 0.f ? 1.f : 0.f) - (l1v < 0.f ? 1.f : 0.f);
    if (!ok || sgn == 0.f) return;
    float rp = R[(size_t)p * 64 + lane];
    float rr = R[(size_t)rev * 64 + lane];
    float m = 0.f;
#pragma unroll
    for (int k = 0; k < 8; ++k)
      m += __shfl(rr, k * 8 + a, 64) * __shfl(rp, k * 8 + b, 64);
    M = -sgn * m;
  } else {
    int v = u - P;
    i = v;
    j = v;
    M = diag[v * 64 + lane];
  }
  float di = Dis[i * 64 + lane];
  float dj = Dis[j * 64 + lane];
  float T = 0.f;
#pragma unroll
  for (int k = 0; k < 8; ++k)
    T += __shfl(M, a * 8 + k, 64) * __shfl(dj, k * 8 + b, 64);
  float o = 0.f;
#pragma unroll
  for (int k = 0; k < 8; ++k)
    o += __shfl(di, a * 8 + k, 64) * __shfl(T, k * 8 + b, 64);
  out[(size_t)(i * Dd + a) * ND + (j * Dd + b)] = o;
}

extern "C" void kernel_launch(void* const* d_in, const int* in_sizes, int n_in,
                              void* d_out, int out_size, void* d_ws, size_t ws_size,
                              hipStream_t stream) {
  const float* R = (const float*)d_in[0];
  const int* eidx = (const int*)d_in[1];
  // d_in[2] = num_edges (device scalar; statically 1024)
  const float* L1 = (const float*)d_in[3];
  float* out = (float*)d_out;
  int P = in_sizes[0] / 64;  // 32768

  int* cnt = (int*)d_ws;                                   // 64 B counters
  float* diag = (float*)((char*)d_ws + 64);                // 256 KiB
  float* Dis = diag + (size_t)N * 64;                      // 256 KiB
  hipMemsetAsync(d_ws, 0, 64 + (size_t)N * 64 * sizeof(float), stream);

  void* args[] = {(void*)&R, (void*)&eidx, (void*)&L1, (void*)&P,
                  (void*)&cnt, (void*)&diag, (void*)&Dis, (void*)&out};
  hipError_t e = hipLaunchCooperativeKernel((const void*)fused, dim3(GRID), dim3(TPB),
                                            args, 0, stream);
  if (e == hipSuccess) return;

  // Fallback: serial multi-kernel path.
  hipMemsetAsync(out, 0, (size_t)out_size * sizeof(float), stream);
  long t1 = (long)P * 64;
  k_build<<<(int)((t1 + 255) / 256), 256, 0, stream>>>(R, eidx, P, diag);
  k_invsqrt<<<(N * 64) / 256, 256, 0, stream>>>(diag, Dis);
  long t3 = (long)(P + N) * 64;
  k_blocks<<<(int)((t3 + 255) / 256), 256, 0, stream>>>(R, eidx, L1, diag, Dis, P, out);
}

// Round 4
// 149.184 us; speedup vs baseline: 1.8275x; 1.8275x over previous
//
#include <hip/hip_runtime.h>
#include <cstddef>
#include <cstdint>

// EdgeSheafLaplacian: n=1024 nodes, stalk d=8, P=32768 directed edges.
// Output Delta (8192 x 8192) f32: only 1024 diag + P edge blocks nonzero.
//
// R4: two dispatches, no memsets, no global atomics, 512 KiB ws.
//   K1 k_diagdis: per-node block scans eidx (L2-resident) for out-edges,
//      accumulates FtF = R^T R via wave shuffles, LDS-reduces, then
//      Newton-Schulz D^{-1/2} (valid: D = sum-of-Wisharts + eps I, so
//      lambda_min >> eps and the reference's clip(w,EPS) is inactive).
//   K2 k_out: per block-row, compute all nonzero normalized blocks into LDS
//      (Dis_i * M * Dis_j), stream 256 KiB of zeros (plain float4 stores;
//      block compute hides under store drain), barrier, scatter from LDS.
// Reverse edge is structural: directed = [lo,hi ; hi,lo] concat -> rev = p +- P/2
// (verified against eidx in-kernel; mismatch -> block stays zero, as reference).

namespace {
constexpr int N = 1024;
constexpr int ND = 8192;
constexpr int MAXB = 100;  // max nonzero blocks per row (deg mean 32, +11sigma < 96)
}

__global__ __launch_bounds__(256) void k_diagdis(const float* __restrict__ R,
                                                 const int* __restrict__ eidx, int P,
                                                 float* __restrict__ diag,
                                                 float* __restrict__ Dis) {
  const int v = blockIdx.x;
  const int tid = threadIdx.x;
  const int wid = tid >> 6, lane = tid & 63;
  const int a = lane >> 3, b = lane & 7;
  const int2* e2 = (const int2*)eidx;
  float acc = 0.f;
  const int chunk = P >> 2;  // per-wave edge range
  const int base = wid * chunk;
  for (int it = 0; it < chunk; it += 64) {
    int2 e = e2[base + it + lane];
    unsigned long long mask = __ballot(e.x == v);
    while (mask) {
      int l = __ffsll(mask) - 1;
      mask &= mask - 1;
      int p = base + it + l;
      float r = R[(size_t)p * 64 + lane];
#pragma unroll
      for (int k = 0; k < 8; ++k)
        acc += __shfl(r, k * 8 + a, 64) * __shfl(r, k * 8 + b, 64);
    }
  }
  __shared__ float part[4][64];
  part[wid][lane] = acc;
  __syncthreads();
  if (wid != 0) return;
  float tot = (part[0][lane] + part[1][lane]) + (part[2][lane] + part[3][lane]);
  diag[v * 64 + lane] = tot;  // bitwise symmetric (same products, same order)
  float A = tot + (a == b ? 1e-4f : 0.f);
  float sq = A * A;
#pragma unroll
  for (int off = 32; off; off >>= 1) sq += __shfl_xor(sq, off, 64);
  float fro = sqrtf(sq);
  // Newton-Schulz coupled iteration: Y0 = A/fro (spectrum in (0,1]), Z0 = I.
  float Y = A * (1.f / fro);
  float Z = (a == b) ? 1.f : 0.f;
  for (int it = 0; it < 13; ++it) {
    float T = 0.f;
#pragma unroll
    for (int k = 0; k < 8; ++k)
      T += __shfl(Z, a * 8 + k, 64) * __shfl(Y, k * 8 + b, 64);
    float G = ((a == b) ? 1.5f : 0.f) - 0.5f * T;  // (3I - ZY)/2
    float Yn = 0.f, Zn = 0.f;
#pragma unroll
    for (int k = 0; k < 8; ++k) {
      Yn += __shfl(Y, a * 8 + k, 64) * __shfl(G, k * 8 + b, 64);
      Zn += __shfl(G, a * 8 + k, 64) * __shfl(Z, k * 8 + b, 64);
    }
    Y = Yn;
    Z = Zn;
  }
  Dis[v * 64 + lane] = Z * (1.f / sqrtf(fro));
}

__global__ __launch_bounds__(256) void k_out(const float* __restrict__ R,
                                             const int* __restrict__ eidx,
                                             const float* __restrict__ L1,
                                             const float* __restrict__ diag,
                                             const float* __restrict__ Dis, int P,
                                             float* __restrict__ out) {
  const int i = blockIdx.x;
  const int tid = threadIdx.x;
  const int wid = tid >> 6, lane = tid & 63;
  const int a = lane >> 3, b = lane & 7;
  __shared__ float Bc[MAXB][64];
  __shared__ int jl[MAXB];
  __shared__ int sCnt;
  if (tid == 0) sCnt = 0;
  __syncthreads();

  const float di = Dis[i * 64 + lane];
  const int2* e2 = (const int2*)eidx;

  // diag block (wave 0): o = Dis_i * diag_i * Dis_i
  if (wid == 0) {
    float M = diag[i * 64 + lane];
    float T = 0.f;
#pragma unroll
    for (int k = 0; k < 8; ++k)
      T += __shfl(M, a * 8 + k, 64) * __shfl(di, k * 8 + b, 64);
    float o = 0.f;
#pragma unroll
    for (int k = 0; k < 8; ++k)
      o += __shfl(di, a * 8 + k, 64) * __shfl(T, k * 8 + b, 64);
    int slot = 0;
    if (lane == 0) slot = atomicAdd(&sCnt, 1);
    slot = __shfl(slot, 0, 64);
    Bc[slot][lane] = o;
    if (lane == 0) jl[slot] = i;
  }

  // scan for out-edges (i -> jb); compute normalized edge blocks into LDS
  const int chunk = P >> 2;
  const int base = wid * chunk;
  const int halfP = P >> 1;
  for (int it = 0; it < chunk; it += 64) {
    int2 e = e2[base + it + lane];
    unsigned long long mask = __ballot(e.x == i);
    while (mask) {
      int l = __ffsll(mask) - 1;
      mask &= mask - 1;
      int p = base + it + l;
      int jb = __shfl(e.y, l, 64);
      int rev = (p < halfP) ? p + halfP : p - halfP;  // structural reverse edge
      bool ok = (eidx[2 * rev] == jb) && (eidx[2 * rev + 1] == i);
      float l1v = L1[i * N + jb];
      float sgn = (l1v > 0.f ? 1.f : 0.f) - (l1v < 0.f ? 1.f : 0.f);
      if (!ok || sgn == 0.f) continue;  // block exactly zero -> leave streamed zeros
      float rp = R[(size_t)p * 64 + lane];
      float rr = R[(size_t)rev * 64 + lane];
      float m = 0.f;
#pragma unroll
      for (int k = 0; k < 8; ++k)
        m += __shfl(rr, k * 8 + a, 64) * __shfl(rp, k * 8 + b, 64);
      float M = -sgn * m;
      float dj = Dis[jb * 64 + lane];
      float T = 0.f;
#pragma unroll
      for (int k = 0; k < 8; ++k)
        T += __shfl(M, a * 8 + k, 64) * __shfl(dj, k * 8 + b, 64);
      float o = 0.f;
#pragma unroll
      for (int k = 0; k < 8; ++k)
        o += __shfl(di, a * 8 + k, 64) * __shfl(T, k * 8 + b, 64);
      int slot = 0;
      if (lane == 0) slot = atomicAdd(&sCnt, 1);
      slot = __shfl(slot, 0, 64);
      if (slot < MAXB) {
        Bc[slot][lane] = o;
        if (lane == 0) jl[slot] = jb;
      }
    }
  }

  // stream zeros for rows [8i, 8i+8): 16384 float4 = 256 KiB, coalesced
  float4 z = {0.f, 0.f, 0.f, 0.f};
  float4* obase = (float4*)(out + (size_t)i * 8 * ND);
#pragma unroll
  for (int t = 0; t < 64; ++t)
    obase[t * 256 + tid] = z;
  __syncthreads();  // drains stores; scatter below lands after

  // scatter nonzero blocks over the zeros (same block -> ordered via barrier)
  int cnt = sCnt < MAXB ? sCnt : MAXB;
  for (int s = wid; s < cnt; s += 4)
    out[(size_t)(i * 8 + a) * ND + jl[s] * 8 + b] = Bc[s][lane];
}

extern "C" void kernel_launch(void* const* d_in, const int* in_sizes, int n_in,
                              void* d_out, int out_size, void* d_ws, size_t ws_size,
                              hipStream_t stream) {
  const float* R = (const float*)d_in[0];
  const int* eidx = (const int*)d_in[1];
  // d_in[2] = num_edges (device scalar; statically 1024)
  const float* L1 = (const float*)d_in[3];
  float* out = (float*)d_out;
  int P = in_sizes[0] / 64;  // 32768

  float* diag = (float*)d_ws;              // 256 KiB
  float* Dis = diag + (size_t)N * 64;      // 256 KiB  (total 512 KiB <= ws)

  k_diagdis<<<N, 256, 0, stream>>>(R, eidx, P, diag, Dis);
  k_out<<<N, 256, 0, stream>>>(R, eidx, L1, diag, Dis, P, out);
}

// Round 5
// 100.968 us; speedup vs baseline: 2.7002x; 1.4775x over previous
//
#include <hip/hip_runtime.h>
#include <cstddef>
#include <cstdint>

// EdgeSheafLaplacian: n=1024 nodes, stalk d=8, P=32768 directed edges.
// Output Delta (8192 x 8192) f32: only 1024 diag + P edge blocks nonzero.
//
// R5: bucket edges by source node (O(P)), then all per-node work is a short
// list walk. Single-pass output write with in-stream block gather.
//   memset cnt (4 KiB)
//   K1 k_count:   rowlist[i] <- p for each directed edge p=(i,j)  (int atomics)
//   K2 k_diagdis: per-node wave: FtF sum over rowlist (no atomics, coalesced
//                 R loads), then Newton-Schulz D^{-1/2}
//                 (valid: D = sum-of-Wisharts + eps I => lambda_min >> eps,
//                  reference's clip(w,EPS) inactive; eigh not needed)
//   K3 k_out:     per block-row i: compute diag + edge blocks into LDS with a
//                 column->slot map, then stream the full 8x8192 row once
//                 (float4), map selecting block values vs zeros.
// Reverse edge is structural: directed = [lo,hi ; hi,lo] concat -> rev = p +- P/2
// (verified in-kernel; mismatch or sign(L1)==0 -> block is exactly zero).

namespace {
constexpr int N = 1024;
constexpr int ND = 8192;
constexpr int MAXB = 96;  // rowlist capacity (deg mean 32, sigma 5.7 -> +11 sigma)
}

__global__ __launch_bounds__(256) void k_count(const int* __restrict__ eidx, int P,
                                               int* __restrict__ cnt,
                                               int* __restrict__ rowlist) {
  int p = blockIdx.x * blockDim.x + threadIdx.x;
  if (p >= P) return;
  int i = ((const int2*)eidx)[p].x;
  int slot = atomicAdd(&cnt[i], 1);
  if (slot < MAXB) rowlist[i * MAXB + slot] = p;
}

__global__ __launch_bounds__(256) void k_diagdis(const float* __restrict__ R,
                                                 const int* __restrict__ cnt,
                                                 const int* __restrict__ rowlist,
                                                 float* __restrict__ diag,
                                                 float* __restrict__ Dis) {
  const int tid = threadIdx.x;
  const int wid = tid >> 6, lane = tid & 63;
  const int a = lane >> 3, b = lane & 7;
  const int v = (blockIdx.x << 2) + wid;
  int c = cnt[v];
  if (c > MAXB) c = MAXB;
  float acc = 0.f;
  for (int s = 0; s < c; ++s) {
    int p = rowlist[v * MAXB + s];
    float r = R[(size_t)p * 64 + lane];
#pragma unroll
    for (int k = 0; k < 8; ++k)
      acc += __shfl(r, k * 8 + a, 64) * __shfl(r, k * 8 + b, 64);
  }
  diag[v * 64 + lane] = acc;  // bitwise symmetric (same products, same order)
  float A = acc + (a == b ? 1e-4f : 0.f);
  float sq = A * A;
#pragma unroll
  for (int off = 32; off; off >>= 1) sq += __shfl_xor(sq, off, 64);
  float fro = sqrtf(sq);
  // Newton-Schulz: Y0 = A/fro (spectrum in (0,1]), Z0 = I; Z -> (A/fro)^{-1/2}
  float Y = A * (1.f / fro);
  float Z = (a == b) ? 1.f : 0.f;
  for (int it = 0; it < 14; ++it) {
    float T = 0.f;
#pragma unroll
    for (int k = 0; k < 8; ++k)
      T += __shfl(Z, a * 8 + k, 64) * __shfl(Y, k * 8 + b, 64);
    float G = ((a == b) ? 1.5f : 0.f) - 0.5f * T;  // (3I - ZY)/2
    float Yn = 0.f, Zn = 0.f;
#pragma unroll
    for (int k = 0; k < 8; ++k) {
      Yn += __shfl(Y, a * 8 + k, 64) * __shfl(G, k * 8 + b, 64);
      Zn += __shfl(G, a * 8 + k, 64) * __shfl(Z, k * 8 + b, 64);
    }
    Y = Yn;
    Z = Zn;
  }
  Dis[v * 64 + lane] = Z * (1.f / sqrtf(fro));
}

__global__ __launch_bounds__(256) void k_out(
    const float* __restrict__ R, const int* __restrict__ eidx,
    const float* __restrict__ L1, const int* __restrict__ cnt,
    const int* __restrict__ rowlist, const float* __restrict__ diag,
    const float* __restrict__ Dis, int P, float* __restrict__ out) {
  const int i = blockIdx.x;
  const int tid = threadIdx.x;
  const int wid = tid >> 6, lane = tid & 63;
  const int a = lane >> 3, b = lane & 7;
  __shared__ float Bc[MAXB + 1][64];
  __shared__ short map[N];  // column-block -> slot, -1 = zero
  for (int t = tid; t < N; t += 256) map[t] = -1;
  __syncthreads();

  const float di = Dis[i * 64 + lane];
  const int halfP = P >> 1;
  int c = cnt[i];
  if (c > MAXB) c = MAXB;

  // diag block -> slot 0
  if (wid == 0) {
    float M = diag[i * 64 + lane];
    float T = 0.f;
#pragma unroll
    for (int k = 0; k < 8; ++k)
      T += __shfl(M, a * 8 + k, 64) * __shfl(di, k * 8 + b, 64);
    float o = 0.f;
#pragma unroll
    for (int k = 0; k < 8; ++k)
      o += __shfl(di, a * 8 + k, 64) * __shfl(T, k * 8 + b, 64);
    Bc[0][lane] = o;
    if (lane == 0) map[i] = 0;
  }

  // edge blocks -> slots 1..c (4 waves strided over the list)
  for (int s = wid; s < c; s += 4) {
    int p = rowlist[i * MAXB + s];
    int jb = eidx[2 * p + 1];
    int rev = (p < halfP) ? p + halfP : p - halfP;  // structural reverse edge
    bool ok = (eidx[2 * rev] == jb) && (eidx[2 * rev + 1] == i);
    float l1v = L1[i * N + jb];
    float sgn = (l1v > 0.f ? 1.f : 0.f) - (l1v < 0.f ? 1.f : 0.f);
    float rp = R[(size_t)p * 64 + lane];
    float rr = R[(size_t)rev * 64 + lane];
    float m = 0.f;
#pragma unroll
    for (int k = 0; k < 8; ++k)
      m += __shfl(rr, k * 8 + a, 64) * __shfl(rp, k * 8 + b, 64);
    float M = ok ? (-sgn * m) : 0.f;
    float dj = Dis[jb * 64 + lane];
    float T = 0.f;
#pragma unroll
    for (int k = 0; k < 8; ++k)
      T += __shfl(M, a * 8 + k, 64) * __shfl(dj, k * 8 + b, 64);
    float o = 0.f;
#pragma unroll
    for (int k = 0; k < 8; ++k)
      o += __shfl(di, a * 8 + k, 64) * __shfl(T, k * 8 + b, 64);
    Bc[s + 1][lane] = o;
    if (lane == 0) map[jb] = (short)(s + 1);
  }
  __syncthreads();

  // single-pass stream of rows [8i, 8i+8): 16384 float4 = 256 KiB
#pragma unroll
  for (int rrow = 0; rrow < 8; ++rrow) {
    float4* orow = (float4*)(out + (size_t)(i * 8 + rrow) * ND);
#pragma unroll
    for (int kk = 0; kk < 8; ++kk) {
      int c4 = kk * 256 + tid;  // 0..2047
      int jb = c4 >> 1, half = c4 & 1;
      int slot = map[jb];
      float4 v = {0.f, 0.f, 0.f, 0.f};
      if (slot >= 0) v = *(const float4*)(&Bc[slot][rrow * 8 + half * 4]);
      orow[c4] = v;
    }
  }
}

extern "C" void kernel_launch(void* const* d_in, const int* in_sizes, int n_in,
                              void* d_out, int out_size, void* d_ws, size_t ws_size,
                              hipStream_t stream) {
  const float* R = (const float*)d_in[0];
  const int* eidx = (const int*)d_in[1];
  // d_in[2] = num_edges (device scalar; statically 1024)
  const float* L1 = (const float*)d_in[3];
  float* out = (float*)d_out;
  int P = in_sizes[0] / 64;  // 32768

  int* cnt = (int*)d_ws;                                    // 4 KiB
  int* rowlist = cnt + N;                                   // 384 KiB
  float* diag = (float*)(rowlist + (size_t)N * MAXB);       // 256 KiB
  float* Dis = diag + (size_t)N * 64;                       // 256 KiB

  hipMemsetAsync(cnt, 0, N * sizeof(int), stream);
  k_count<<<P / 256, 256, 0, stream>>>(eidx, P, cnt, rowlist);
  k_diagdis<<<N / 4, 256, 0, stream>>>(R, cnt, rowlist, diag, Dis);
  k_out<<<N, 256, 0, stream>>>(R, eidx, L1, cnt, rowlist, diag, Dis, P, out);
}